// Round 2
// baseline (191.932 us; speedup 1.0000x reference)
//
#include <hip/hip_runtime.h>
#include <math.h>

// Problem constants
#define F_IN  256
#define NOUT  256          // N_HEADS * N_HIDDEN
#define NB    8            // batch
#define NN    1024         // nodes
#define NH    8            // heads
#define ND    32           // hidden per head
#define NROWS (NB * NN)    // 8192
#define LOG2E 1.44269504f

// ---------------------------------------------------------------------------
// Kernel 1: g = vertex @ w_vert (8192x256 @ 256x256) fp32.
// Tile 64 rows x 32 cols (= one head), 256 threads, 2x4 micro-tile, TK=32.
// Register-prefetch of next k-chunk overlaps global latency with FMAs.
// Epilogue: s_src/s_dst via dot + 3-step shuffle-xor over the 8 col-threads.
// Grid (8 heads, 128 row-tiles) = 1024 WGs -> 4 per CU.
// ---------------------------------------------------------------------------
__global__ __launch_bounds__(256) void gat_gemm_kernel(
    const float* __restrict__ vertex, const float* __restrict__ w_vert,
    const float* __restrict__ attn_w, float* __restrict__ g,
    float* __restrict__ s_src, float* __restrict__ s_dst)
{
    __shared__ __align__(16) float a_lds[32][66];   // transposed: [k][row], stride 66 -> 2-way max
    __shared__ __align__(16) float b_lds[32][36];   // [k][col]

    const int tid = threadIdx.x;
    const int h   = blockIdx.x;          // head == 32-col tile
    const int gc0 = h * ND;
    const int gr0 = blockIdx.y * 64;

    const int rt = tid >> 3;             // 0..31 -> rows rt*2
    const int ct = tid & 7;              // cols ct*4

    float4 a_reg[2], b_reg;
    const int bk  = tid >> 3;            // 0..31
    const int bcq = (tid & 7) * 4;

    // prefetch chunk 0
    #pragma unroll
    for (int q = 0; q < 2; ++q) {
        const int f = tid + 256 * q, arow = f >> 3, akq = (f & 7) * 4;
        a_reg[q] = *(const float4*)&vertex[(size_t)(gr0 + arow) * F_IN + akq];
    }
    b_reg = *(const float4*)&w_vert[(size_t)bk * NOUT + gc0 + bcq];

    float acc[2][4] = {};

    for (int c = 0; c < 8; ++c) {
        if (c) __syncthreads();
        #pragma unroll
        for (int q = 0; q < 2; ++q) {
            const int f = tid + 256 * q, arow = f >> 3, akq = (f & 7) * 4;
            a_lds[akq + 0][arow] = a_reg[q].x;
            a_lds[akq + 1][arow] = a_reg[q].y;
            a_lds[akq + 2][arow] = a_reg[q].z;
            a_lds[akq + 3][arow] = a_reg[q].w;
        }
        *(float4*)&b_lds[bk][bcq] = b_reg;
        __syncthreads();

        if (c < 7) {   // issue next chunk's loads; compiler overlaps with FMAs below
            const int k0 = (c + 1) * 32;
            #pragma unroll
            for (int q = 0; q < 2; ++q) {
                const int f = tid + 256 * q, arow = f >> 3, akq = (f & 7) * 4;
                a_reg[q] = *(const float4*)&vertex[(size_t)(gr0 + arow) * F_IN + k0 + akq];
            }
            b_reg = *(const float4*)&w_vert[(size_t)(k0 + bk) * NOUT + gc0 + bcq];
        }

        #pragma unroll
        for (int kk = 0; kk < 32; ++kk) {
            float2 av = *(const float2*)&a_lds[kk][rt * 2];
            float4 bv = *(const float4*)&b_lds[kk][ct * 4];
            acc[0][0] += av.x * bv.x; acc[0][1] += av.x * bv.y;
            acc[0][2] += av.x * bv.z; acc[0][3] += av.x * bv.w;
            acc[1][0] += av.y * bv.x; acc[1][1] += av.y * bv.y;
            acc[1][2] += av.y * bv.z; acc[1][3] += av.y * bv.w;
        }
    }

    // write g
    #pragma unroll
    for (int u = 0; u < 2; ++u) {
        float4 o = {acc[u][0], acc[u][1], acc[u][2], acc[u][3]};
        *(float4*)&g[(size_t)(gr0 + rt * 2 + u) * NOUT + gc0 + ct * 4] = o;
    }

    // epilogue: scores for head h; reduce over ct (lane bits 0..2)
    const int dl = ct * 4;
    float4 ws4 = *(const float4*)&attn_w[dl];
    float4 wd4 = *(const float4*)&attn_w[ND + dl];
    #pragma unroll
    for (int u = 0; u < 2; ++u) {
        float ps = acc[u][0] * ws4.x + acc[u][1] * ws4.y +
                   acc[u][2] * ws4.z + acc[u][3] * ws4.w;
        float pd = acc[u][0] * wd4.x + acc[u][1] * wd4.y +
                   acc[u][2] * wd4.z + acc[u][3] * wd4.w;
        #pragma unroll
        for (int off = 1; off < 8; off <<= 1) {
            ps += __shfl_xor(ps, off);
            pd += __shfl_xor(pd, off);
        }
        if (ct == 0) {
            const int row = gr0 + rt * 2 + u;
            s_src[row * NH + h] = ps;
            s_dst[row * NH + h] = pd;
        }
    }
}

// ---------------------------------------------------------------------------
// Kernel 2: out[b,i,h,:] = sum_j softmax_j(lrelu(s_src[i]+s_dst[j])) g[b,j,h,:]
// One WG per (b, h, 64-row i-block): grid 1024 WGs, 256 threads, LDS 29 KB
// -> 4 resident WGs/CU (grid-limited; LDS cap is 5).
// Phase 1: thread covers 4 rows x 64 j (sd read amortized over 4 rows).
// Phase 2: 64-j chunks; p-chunk [j][i] + g-chunk in LDS; 2i x 4d micro-tiles.
// ---------------------------------------------------------------------------
__global__ __launch_bounds__(256) void gat_attn_kernel(
    const float* __restrict__ g, const float* __restrict__ s_src,
    const float* __restrict__ s_dst, float* __restrict__ out)
{
    __shared__ __align__(16) float sd[NN];        // 4 KB
    __shared__ __align__(16) float ss[64];
    __shared__ __align__(16) float mk[64];        // m_i * log2e
    __shared__ __align__(16) float rr[64];        // 1 / l_i
    __shared__ __align__(16) float gj[64][32];    // 8 KB
    __shared__ __align__(16) float pj[64][64];    // 16 KB

    const int b  = blockIdx.z;
    const int h  = blockIdx.y;
    const int i0 = blockIdx.x * 64;
    const int t  = threadIdx.x;

    // ---- phase 0: stage score vectors ----
    #pragma unroll
    for (int q = 0; q < 4; ++q) {
        const int j = t + 256 * q;
        sd[j] = s_dst[(size_t)(b * NN + j) * NH + h];
    }
    if (t < 64) ss[t] = s_src[(size_t)(b * NN + i0 + t) * NH + h];
    __syncthreads();

    // ---- phase 1: exact m_i, 1/l_i. thread = 4 rows x 64 j ----
    {
        const int rq = t >> 4;        // 0..15 -> rows rq*4..+3
        const int jq = t & 15;        // j = jj*16 + jq (conflict-free broadcast)
        float si[4], m[4], s[4];
        #pragma unroll
        for (int u = 0; u < 4; ++u) { si[u] = ss[rq * 4 + u]; m[u] = -3.0e38f; }

        #pragma unroll 8
        for (int jj = 0; jj < 64; ++jj) {
            const float sdv = sd[jj * 16 + jq];
            #pragma unroll
            for (int u = 0; u < 4; ++u) {
                float x = si[u] + sdv;
                x = fmaxf(x, 0.2f * x);
                m[u] = fmaxf(m[u], x);
            }
        }
        #pragma unroll
        for (int off = 1; off < 16; off <<= 1)
            #pragma unroll
            for (int u = 0; u < 4; ++u)
                m[u] = fmaxf(m[u], __shfl_xor(m[u], off));
        #pragma unroll
        for (int u = 0; u < 4; ++u) { m[u] *= LOG2E; s[u] = 0.f; }

        #pragma unroll 8
        for (int jj = 0; jj < 64; ++jj) {
            const float sdv = sd[jj * 16 + jq];
            #pragma unroll
            for (int u = 0; u < 4; ++u) {
                float x = si[u] + sdv;
                x = fmaxf(x, 0.2f * x);
                s[u] += exp2f(fmaf(x, LOG2E, -m[u]));
            }
        }
        #pragma unroll
        for (int off = 1; off < 16; off <<= 1)
            #pragma unroll
            for (int u = 0; u < 4; ++u)
                s[u] += __shfl_xor(s[u], off);
        if (jq == 0) {
            #pragma unroll
            for (int u = 0; u < 4; ++u) {
                mk[rq * 4 + u] = m[u];
                rr[rq * 4 + u] = 1.0f / s[u];
            }
        }
    }
    __syncthreads();

    // ---- phase 2: j-chunks of 64 ----
    const int it  = t >> 3;           // 0..31 -> rows it*2
    const int dt  = t & 7;            // cols dt*4
    const int piq = (t & 15) * 4;     // thread-constant i-offset for 2b
    const int pjb = t >> 4;           // jj = pjb + 16k in 2b

    // hoisted per-thread softmax constants for 2b
    const float4 s4 = *(const float4*)&ss[piq];
    const float4 m4 = *(const float4*)&mk[piq];
    const float4 r4 = *(const float4*)&rr[piq];

    float acc[2][4] = {};

    for (int jc = 0; jc < NN; jc += 64) {
        if (jc) __syncthreads();

        // 2a: stage g chunk (64 x 32)
        #pragma unroll
        for (int q = 0; q < 2; ++q) {
            const int f  = t + 256 * q;
            const int jj = f >> 3;
            const int dq = (f & 7) * 4;
            *(float4*)&gj[jj][dq] =
                *(const float4*)&g[(size_t)(b * NN + jc + jj) * NOUT + h * ND + dq];
        }
        // 2b: normalized p chunk (64 x 64), [j][i] layout
        #pragma unroll
        for (int k = 0; k < 4; ++k) {
            const int jj  = pjb + 16 * k;
            const float sdj = sd[jc + jj];
            float4 p; float x;
            x = s4.x + sdj; x = fmaxf(x, 0.2f * x); p.x = exp2f(fmaf(x, LOG2E, -m4.x)) * r4.x;
            x = s4.y + sdj; x = fmaxf(x, 0.2f * x); p.y = exp2f(fmaf(x, LOG2E, -m4.y)) * r4.y;
            x = s4.z + sdj; x = fmaxf(x, 0.2f * x); p.z = exp2f(fmaf(x, LOG2E, -m4.z)) * r4.z;
            x = s4.w + sdj; x = fmaxf(x, 0.2f * x); p.w = exp2f(fmaf(x, LOG2E, -m4.w)) * r4.w;
            *(float4*)&pj[jj][piq] = p;
        }
        __syncthreads();

        // 2c: acc[i][d] += p[j][i] * g[j][d]
        #pragma unroll 16
        for (int jj = 0; jj < 64; ++jj) {
            float2 pv = *(const float2*)&pj[jj][it * 2];
            float4 gv = *(const float4*)&gj[jj][dt * 4];
            acc[0][0] += pv.x * gv.x; acc[0][1] += pv.x * gv.y;
            acc[0][2] += pv.x * gv.z; acc[0][3] += pv.x * gv.w;
            acc[1][0] += pv.y * gv.x; acc[1][1] += pv.y * gv.y;
            acc[1][2] += pv.y * gv.z; acc[1][3] += pv.y * gv.w;
        }
    }

    // ---- phase 3: write out ----
    #pragma unroll
    for (int u = 0; u < 2; ++u) {
        float4 o = {acc[u][0], acc[u][1], acc[u][2], acc[u][3]};
        *(float4*)&out[(size_t)(b * NN + i0 + it * 2 + u) * NOUT + h * ND + dt * 4] = o;
    }
}

// ---------------------------------------------------------------------------
extern "C" void kernel_launch(void* const* d_in, const int* in_sizes, int n_in,
                              void* d_out, int out_size, void* d_ws, size_t ws_size,
                              hipStream_t stream) {
    (void)in_sizes; (void)n_in; (void)out_size; (void)ws_size;
    const float* vertex = (const float*)d_in[0];
    const float* w_vert = (const float*)d_in[1];
    const float* attn_w = (const float*)d_in[2];
    float* out = (float*)d_out;

    float* g     = (float*)d_ws;                       // 8 MB
    float* s_src = g + (size_t)NROWS * NOUT;           // 256 KB
    float* s_dst = s_src + (size_t)NROWS * NH;         // 256 KB

    gat_gemm_kernel<<<dim3(NH, 128), 256, 0, stream>>>(vertex, w_vert, attn_w,
                                                       g, s_src, s_dst);
    gat_attn_kernel<<<dim3(16, NH, NB), 256, 0, stream>>>(g, s_src, s_dst, out);
}

// Round 3
// 120.519 us; speedup vs baseline: 1.5925x; 1.5925x over previous
//
#include <hip/hip_runtime.h>
#include <hip/hip_bf16.h>
#include <math.h>

// Problem constants
#define F_IN  256
#define NOUT  256          // N_HEADS * N_HIDDEN
#define NB    8            // batch
#define NN    1024         // nodes
#define NH    8            // heads
#define ND    32           // hidden per head
#define NROWS (NB * NN)    // 8192
#define LOG2E 1.44269504f

typedef __attribute__((ext_vector_type(8))) short bf16x8;   // 8 bf16 = 4 VGPRs
typedef __attribute__((ext_vector_type(4))) float f32x4;    // MFMA C/D

__device__ inline unsigned pk_bf16(float a, float b) {
    union { __hip_bfloat162 h2; unsigned u; } c;
    c.h2 = __float22bfloat162_rn(make_float2(a, b));
    return c.u;
}
__device__ inline unsigned short bf16u(float a) {
    union { __hip_bfloat16 h; unsigned short u; } c;
    c.h = __float2bfloat16(a);
    return c.u;
}

// ---------------------------------------------------------------------------
// Kernel 1: fp32 GEMM g = vertex @ w_vert (8192x256 @ 256x256).
// Outputs: gT bf16 [b][h][d][j] (for attn B-frags) + exact fp32 scores
// ssT/sdT [b][h][j]. No fp32 g is written (attn doesn't need it).
// Tile 64x64 (2 heads), 256 thr, 4x4 micro, TK=32, register prefetch.
// Per kk: 2x ds_read_b128 per 16 FMAs -> VALU/LDS balanced (vs 2 per 8 in R2).
// ---------------------------------------------------------------------------
__global__ __launch_bounds__(256) void gat_gemm_kernel(
    const float* __restrict__ vertex, const float* __restrict__ w_vert,
    const float* __restrict__ attn_w, unsigned short* __restrict__ gT,
    float* __restrict__ ssT, float* __restrict__ sdT)
{
    __shared__ __align__(16) float a_lds[32][68];   // [k][row] transposed
    __shared__ __align__(16) float b_lds[32][68];   // [k][col]

    const int tid = threadIdx.x;
    const int gc0 = blockIdx.x * 64;
    const int gr0 = blockIdx.y * 64;

    const int tr = tid >> 4;          // rows tr*4
    const int tc = tid & 15;          // cols tc*4

    float4 a_reg[2], b_reg[2];
    #pragma unroll
    for (int q = 0; q < 2; ++q) {
        const int f = tid + 256 * q;
        a_reg[q] = *(const float4*)&vertex[(gr0 + (f >> 3)) * F_IN + (f & 7) * 4];
        b_reg[q] = *(const float4*)&w_vert[(f >> 4) * NOUT + gc0 + (f & 15) * 4];
    }

    float acc[4][4] = {};

    for (int c = 0; c < 8; ++c) {
        if (c) __syncthreads();
        #pragma unroll
        for (int q = 0; q < 2; ++q) {
            const int f = tid + 256 * q;
            const int ar = f >> 3, ak = (f & 7) * 4;
            a_lds[ak + 0][ar] = a_reg[q].x;
            a_lds[ak + 1][ar] = a_reg[q].y;
            a_lds[ak + 2][ar] = a_reg[q].z;
            a_lds[ak + 3][ar] = a_reg[q].w;
            *(float4*)&b_lds[f >> 4][(f & 15) * 4] = b_reg[q];
        }
        __syncthreads();
        if (c < 7) {
            const int k0 = (c + 1) * 32;
            #pragma unroll
            for (int q = 0; q < 2; ++q) {
                const int f = tid + 256 * q;
                a_reg[q] = *(const float4*)&vertex[(gr0 + (f >> 3)) * F_IN + k0 + (f & 7) * 4];
                b_reg[q] = *(const float4*)&w_vert[(k0 + (f >> 4)) * NOUT + gc0 + (f & 15) * 4];
            }
        }
        #pragma unroll
        for (int kk = 0; kk < 32; ++kk) {
            float4 va = *(const float4*)&a_lds[kk][tr * 4];
            float4 vb = *(const float4*)&b_lds[kk][tc * 4];
            float af[4] = {va.x, va.y, va.z, va.w};
            float bf[4] = {vb.x, vb.y, vb.z, vb.w};
            #pragma unroll
            for (int ri = 0; ri < 4; ++ri)
                #pragma unroll
                for (int ci = 0; ci < 4; ++ci)
                    acc[ri][ci] += af[ri] * bf[ci];
        }
    }

    // epilogue: bf16 transposed g + exact fp32 scores
    const int hx    = blockIdx.x * 2 + (tc >> 3);   // global head
    const int dbase = (tc & 7) * 4;                 // d within head
    float4 ws4 = *(const float4*)&attn_w[dbase];
    float4 wd4 = *(const float4*)&attn_w[ND + dbase];

    #pragma unroll
    for (int ri = 0; ri < 4; ++ri) {
        const int row = gr0 + tr * 4 + ri;
        const int bb = row >> 10, jn = row & 1023;
        unsigned short* gp = gT + ((size_t)((bb * NH + hx) * ND + dbase)) * NN + jn;
        gp[0 * NN] = bf16u(acc[ri][0]);
        gp[1 * NN] = bf16u(acc[ri][1]);
        gp[2 * NN] = bf16u(acc[ri][2]);
        gp[3 * NN] = bf16u(acc[ri][3]);

        float ps = acc[ri][0] * ws4.x + acc[ri][1] * ws4.y +
                   acc[ri][2] * ws4.z + acc[ri][3] * ws4.w;
        float pd = acc[ri][0] * wd4.x + acc[ri][1] * wd4.y +
                   acc[ri][2] * wd4.z + acc[ri][3] * wd4.w;
        #pragma unroll
        for (int off = 1; off < 8; off <<= 1) {
            ps += __shfl_xor(ps, off);
            pd += __shfl_xor(pd, off);
        }
        if ((tc & 7) == 0) {
            ssT[(bb * NH + hx) * NN + jn] = ps;
            sdT[(bb * NH + hx) * NN + jn] = pd;
        }
    }
}

// ---------------------------------------------------------------------------
// Kernel 2 (MFMA): out[b,i,h,:] = (sum_j q_ij * g[j,:]) / (sum_j q_ij),
// q_ij = exp(lrelu(ss_i + sd_j) - m_i), m_i = lrelu(ss_i + max_j sd_j)
// (exact: lrelu monotone). No N^2 denominator pass, no p-matrix in LDS.
// WG = (b, h, 64-i-block), 4 waves, wave owns 16 i-rows x 32 d.
// Per k-step (32 j): A-frag (q) generated in registers in MFMA A-layout;
// B-frags (g bf16) loaded 16 B/lane DIRECTLY from global gT (L2/L3-hot).
// No barriers in the k-loop.
// ---------------------------------------------------------------------------
__global__ __launch_bounds__(256) void gat_attn_kernel(
    const unsigned short* __restrict__ gT, const float* __restrict__ ssT,
    const float* __restrict__ sdT, float* __restrict__ out)
{
    __shared__ __align__(16) float sd_lds[NN];   // 4 KB
    __shared__ float red[4];
    __shared__ float rs_lds[64];                 // 1/S per i-row

    const int b  = blockIdx.z;
    const int h  = blockIdx.y;
    const int i0 = blockIdx.x * 64;
    const int t  = threadIdx.x;
    const int lane = t & 63, w = t >> 6;
    const int bh = b * NH + h;

    // stage sd + exact global max over j
    float M = -3.0e38f;
    #pragma unroll
    for (int q = 0; q < 4; ++q) {
        const float v = sdT[bh * NN + t + 256 * q];
        sd_lds[t + 256 * q] = v;
        M = fmaxf(M, v);
    }
    #pragma unroll
    for (int off = 32; off >= 1; off >>= 1)
        M = fmaxf(M, __shfl_xor(M, off));
    if (lane == 0) red[w] = M;
    __syncthreads();
    M = fmaxf(fmaxf(red[0], red[1]), fmaxf(red[2], red[3]));

    const int il = lane & 15;    // i-row within wave tile (A m-index)
    const int ql = lane >> 4;    // k-group (A/B k-index base = ql*8)
    const float si = ssT[bh * NN + i0 + w * 16 + il];
    float xm = si + M; xm = fmaxf(xm, 0.2f * xm);
    const float mk = xm * LOG2E;               // row max in log2 domain

    const unsigned short* gb0 = gT + ((size_t)(bh * ND) + il) * NN + ql * 8;
    const unsigned short* gb1 = gb0 + 16 * NN;

    f32x4 c0 = {0.f, 0.f, 0.f, 0.f}, c1 = {0.f, 0.f, 0.f, 0.f};
    float S = 0.f;

    #pragma unroll 4
    for (int k0 = 0; k0 < NN; k0 += 32) {
        const float4 s0 = *(const float4*)&sd_lds[k0 + ql * 8];
        const float4 s1 = *(const float4*)&sd_lds[k0 + ql * 8 + 4];
        const bf16x8 bf0 = *(const bf16x8*)(gb0 + k0);
        const bf16x8 bf1 = *(const bf16x8*)(gb1 + k0);

        float e0, e1, e2, e3, e4, e5, e6, e7, x;
        x = si + s0.x; x = fmaxf(x, 0.2f * x); e0 = exp2f(fmaf(x, LOG2E, -mk));
        x = si + s0.y; x = fmaxf(x, 0.2f * x); e1 = exp2f(fmaf(x, LOG2E, -mk));
        x = si + s0.z; x = fmaxf(x, 0.2f * x); e2 = exp2f(fmaf(x, LOG2E, -mk));
        x = si + s0.w; x = fmaxf(x, 0.2f * x); e3 = exp2f(fmaf(x, LOG2E, -mk));
        x = si + s1.x; x = fmaxf(x, 0.2f * x); e4 = exp2f(fmaf(x, LOG2E, -mk));
        x = si + s1.y; x = fmaxf(x, 0.2f * x); e5 = exp2f(fmaf(x, LOG2E, -mk));
        x = si + s1.z; x = fmaxf(x, 0.2f * x); e6 = exp2f(fmaf(x, LOG2E, -mk));
        x = si + s1.w; x = fmaxf(x, 0.2f * x); e7 = exp2f(fmaf(x, LOG2E, -mk));
        S += ((e0 + e1) + (e2 + e3)) + ((e4 + e5) + (e6 + e7));

        union { bf16x8 v; unsigned u[4]; } af;
        af.u[0] = pk_bf16(e0, e1);
        af.u[1] = pk_bf16(e2, e3);
        af.u[2] = pk_bf16(e4, e5);
        af.u[3] = pk_bf16(e6, e7);

        c0 = __builtin_amdgcn_mfma_f32_16x16x32_bf16(af.v, bf0, c0, 0, 0, 0);
        c1 = __builtin_amdgcn_mfma_f32_16x16x32_bf16(af.v, bf1, c1, 0, 0, 0);
    }

    // complete S_i across the 4 k-groups (lanes sharing il)
    S += __shfl_xor(S, 16);
    S += __shfl_xor(S, 32);
    if (lane < 16) rs_lds[w * 16 + lane] = 1.0f / S;
    __syncthreads();

    // C/D layout (16x16x32): col = lane&15 (d), row = ql*4 + reg (i)
    const int rbase = w * 16 + ql * 4;
    const float r0 = rs_lds[rbase + 0];
    const float r1 = rs_lds[rbase + 1];
    const float r2 = rs_lds[rbase + 2];
    const float r3 = rs_lds[rbase + 3];

    float* ob = out + (size_t)(b * NN + i0 + rbase) * NOUT + h * ND + il;
    ob[0 * NOUT]      = c0[0] * r0;
    ob[1 * NOUT]      = c0[1] * r1;
    ob[2 * NOUT]      = c0[2] * r2;
    ob[3 * NOUT]      = c0[3] * r3;
    ob[0 * NOUT + 16] = c1[0] * r0;
    ob[1 * NOUT + 16] = c1[1] * r1;
    ob[2 * NOUT + 16] = c1[2] * r2;
    ob[3 * NOUT + 16] = c1[3] * r3;
}

// ---------------------------------------------------------------------------
extern "C" void kernel_launch(void* const* d_in, const int* in_sizes, int n_in,
                              void* d_out, int out_size, void* d_ws, size_t ws_size,
                              hipStream_t stream) {
    (void)in_sizes; (void)n_in; (void)out_size; (void)ws_size;
    const float* vertex = (const float*)d_in[0];
    const float* w_vert = (const float*)d_in[1];
    const float* attn_w = (const float*)d_in[2];
    float* out = (float*)d_out;

    unsigned short* gT = (unsigned short*)d_ws;                 // 4 MB bf16 g^T
    float* ssT = (float*)((char*)d_ws + (size_t)NB * NH * ND * NN * 2);
    float* sdT = ssT + (size_t)NB * NH * NN;

    gat_gemm_kernel<<<dim3(4, 128), 256, 0, stream>>>(vertex, w_vert, attn_w,
                                                      gT, ssT, sdT);
    gat_attn_kernel<<<dim3(16, NH, NB), 256, 0, stream>>>(gT, ssT, sdT, out);
}

// Round 4
// 108.585 us; speedup vs baseline: 1.7676x; 1.1099x over previous
//
#include <hip/hip_runtime.h>
#include <hip/hip_bf16.h>
#include <math.h>

// Problem constants
#define F_IN  256
#define NOUT  256          // N_HEADS * N_HIDDEN
#define NB    8            // batch
#define NN    1024         // nodes
#define NH    8            // heads
#define ND    32           // hidden per head
#define NROWS (NB * NN)    // 8192
#define LOG2E 1.44269504f

typedef __attribute__((ext_vector_type(8))) short bf16x8;   // 8 bf16 = 4 VGPRs
typedef __attribute__((ext_vector_type(4))) float f32x4;    // MFMA C/D

__device__ inline unsigned pk_bf16(float a, float b) {
    union { __hip_bfloat162 h2; unsigned u; } c;
    c.h2 = __float22bfloat162_rn(make_float2(a, b));
    return c.u;
}
__device__ inline unsigned short bf16u(float a) {
    union { __hip_bfloat16 h; unsigned short u; } c;
    c.h = __float2bfloat16(a);
    return c.u;
}
__device__ inline float bf2f(unsigned short u) {
    union { unsigned u; float f; } c;
    c.u = ((unsigned)u) << 16;
    return c.f;
}
// split 8 fp32 into hi/lo bf16 fragments (hi = rn(x), lo = rn(x - hi))
__device__ inline void split8(const float4 va, const float4 vb,
                              bf16x8& hi, bf16x8& lo) {
    float f[8] = {va.x, va.y, va.z, va.w, vb.x, vb.y, vb.z, vb.w};
    union { bf16x8 v; unsigned u[4]; } H, L;
    #pragma unroll
    for (int i = 0; i < 4; ++i) {
        unsigned short h0 = bf16u(f[2 * i]);
        unsigned short h1 = bf16u(f[2 * i + 1]);
        H.u[i] = (unsigned)h0 | ((unsigned)h1 << 16);
        L.u[i] = pk_bf16(f[2 * i] - bf2f(h0), f[2 * i + 1] - bf2f(h1));
    }
    hi = H.v; lo = L.v;
}

// ---------------------------------------------------------------------------
// Kernel 0: wT_hi/wT_lo [n][k] bf16 split of w_vert [k][n] fp32 (one-time).
// ---------------------------------------------------------------------------
__global__ __launch_bounds__(256) void w_prep_kernel(
    const float* __restrict__ w_vert,
    unsigned short* __restrict__ wT_hi, unsigned short* __restrict__ wT_lo)
{
    __shared__ float wf[64][68];
    const int t  = threadIdx.x;
    const int kt = (blockIdx.x >> 2) * 64;
    const int nt = (blockIdx.x & 3) * 64;
    #pragma unroll
    for (int q = 0; q < 4; ++q) {
        const int kr = (t >> 4) + 16 * q;
        const int nc = (t & 15) * 4;
        float4 v = *(const float4*)&w_vert[(size_t)(kt + kr) * NOUT + nt + nc];
        wf[kr][nc + 0] = v.x; wf[kr][nc + 1] = v.y;
        wf[kr][nc + 2] = v.z; wf[kr][nc + 3] = v.w;
    }
    __syncthreads();
    const int n = t >> 2, ks = (t & 3) * 16;
    union { unsigned u[8]; } Hs, Ls;
    #pragma unroll
    for (int i = 0; i < 8; ++i) {
        float x0 = wf[ks + 2 * i][n], x1 = wf[ks + 2 * i + 1][n];
        unsigned short h0 = bf16u(x0), h1 = bf16u(x1);
        Hs.u[i] = (unsigned)h0 | ((unsigned)h1 << 16);
        Ls.u[i] = pk_bf16(x0 - bf2f(h0), x1 - bf2f(h1));
    }
    unsigned* ph = (unsigned*)(wT_hi + (size_t)(nt + n) * F_IN + kt + ks);
    unsigned* pl = (unsigned*)(wT_lo + (size_t)(nt + n) * F_IN + kt + ks);
    #pragma unroll
    for (int i = 0; i < 8; ++i) { ph[i] = Hs.u[i]; pl[i] = Ls.u[i]; }
}

// ---------------------------------------------------------------------------
// Kernel 1: g = vertex @ w_vert via split-bf16 MFMA (hi*hi + lo*hi + hi*lo,
// rel err ~2^-17 => scores effectively fp32-exact). Barrier-free k-loop:
// A-frags from global fp32 + register split; B-frags from global wT bf16.
// WG 64x64 (2 heads), 4 waves 2x2, wave 32x32, 12 MFMAs/k-step.
// Epilogue: gT bf16 [bh][d][j] + exact fp32 scores ssT/sdT [bh][j].
// ---------------------------------------------------------------------------
__global__ __launch_bounds__(256) void gat_gemm_kernel(
    const float* __restrict__ vertex,
    const unsigned short* __restrict__ wT_hi,
    const unsigned short* __restrict__ wT_lo,
    const float* __restrict__ attn_w, unsigned short* __restrict__ gT,
    float* __restrict__ ssT, float* __restrict__ sdT)
{
    const int t = threadIdx.x, lane = t & 63, wv = t >> 6;
    const int wx = wv & 1, wy = wv >> 1;
    const int il = lane & 15, ql = lane >> 4;
    const int gc0 = blockIdx.x * 64, gr0 = blockIdx.y * 64;
    const int hx = blockIdx.x * 2 + wx;
    const int b  = gr0 >> 10;
    const int bh = b * NH + hx;

    const float* arow0 = vertex + (size_t)(gr0 + wy * 32 + il) * F_IN + ql * 8;
    const float* arow1 = arow0 + 16 * F_IN;
    const unsigned short* b0h = wT_hi + (size_t)(gc0 + wx * 32 + il) * F_IN + ql * 8;
    const unsigned short* b1h = b0h + 16 * F_IN;
    const unsigned short* b0l = wT_lo + (size_t)(gc0 + wx * 32 + il) * F_IN + ql * 8;
    const unsigned short* b1l = b0l + 16 * F_IN;

    f32x4 c00 = {0.f, 0.f, 0.f, 0.f}, c01 = c00, c10 = c00, c11 = c00;

    #pragma unroll 2
    for (int k0 = 0; k0 < F_IN; k0 += 32) {
        float4 a0a = *(const float4*)(arow0 + k0);
        float4 a0b = *(const float4*)(arow0 + k0 + 4);
        float4 a1a = *(const float4*)(arow1 + k0);
        float4 a1b = *(const float4*)(arow1 + k0 + 4);
        bf16x8 bh0 = *(const bf16x8*)(b0h + k0);
        bf16x8 bh1 = *(const bf16x8*)(b1h + k0);
        bf16x8 bl0 = *(const bf16x8*)(b0l + k0);
        bf16x8 bl1 = *(const bf16x8*)(b1l + k0);

        bf16x8 a0hi, a0lo, a1hi, a1lo;
        split8(a0a, a0b, a0hi, a0lo);
        split8(a1a, a1b, a1hi, a1lo);

        c00 = __builtin_amdgcn_mfma_f32_16x16x32_bf16(a0hi, bh0, c00, 0, 0, 0);
        c01 = __builtin_amdgcn_mfma_f32_16x16x32_bf16(a0hi, bh1, c01, 0, 0, 0);
        c10 = __builtin_amdgcn_mfma_f32_16x16x32_bf16(a1hi, bh0, c10, 0, 0, 0);
        c11 = __builtin_amdgcn_mfma_f32_16x16x32_bf16(a1hi, bh1, c11, 0, 0, 0);
        c00 = __builtin_amdgcn_mfma_f32_16x16x32_bf16(a0lo, bh0, c00, 0, 0, 0);
        c01 = __builtin_amdgcn_mfma_f32_16x16x32_bf16(a0lo, bh1, c01, 0, 0, 0);
        c10 = __builtin_amdgcn_mfma_f32_16x16x32_bf16(a1lo, bh0, c10, 0, 0, 0);
        c11 = __builtin_amdgcn_mfma_f32_16x16x32_bf16(a1lo, bh1, c11, 0, 0, 0);
        c00 = __builtin_amdgcn_mfma_f32_16x16x32_bf16(a0hi, bl0, c00, 0, 0, 0);
        c01 = __builtin_amdgcn_mfma_f32_16x16x32_bf16(a0hi, bl1, c01, 0, 0, 0);
        c10 = __builtin_amdgcn_mfma_f32_16x16x32_bf16(a1hi, bl0, c10, 0, 0, 0);
        c11 = __builtin_amdgcn_mfma_f32_16x16x32_bf16(a1hi, bl1, c11, 0, 0, 0);
    }

    // epilogue: gT + scores. C/D: col=il (n within tile), row=ql*4+reg (m).
    const int j0 = (gr0 & 1023) + wy * 32;
    const float wsv0 = attn_w[il],      wsv1 = attn_w[16 + il];
    const float wdv0 = attn_w[ND + il], wdv1 = attn_w[ND + 16 + il];

    #pragma unroll
    for (int mt = 0; mt < 2; ++mt) {
        f32x4 cA = mt ? c10 : c00;   // n-tile 0: d = il
        f32x4 cB = mt ? c11 : c01;   // n-tile 1: d = 16+il
        const int jr = j0 + mt * 16 + ql * 4;

        unsigned g2[2];
        g2[0] = pk_bf16(cA[0], cA[1]); g2[1] = pk_bf16(cA[2], cA[3]);
        *(uint2*)(gT + ((size_t)(bh * ND) + il) * NN + jr) = *(uint2*)g2;
        g2[0] = pk_bf16(cB[0], cB[1]); g2[1] = pk_bf16(cB[2], cB[3]);
        *(uint2*)(gT + ((size_t)(bh * ND) + 16 + il) * NN + jr) = *(uint2*)g2;

        #pragma unroll
        for (int reg = 0; reg < 4; ++reg) {
            float ps = cA[reg] * wsv0 + cB[reg] * wsv1;
            float pd = cA[reg] * wdv0 + cB[reg] * wdv1;
            #pragma unroll
            for (int off = 1; off < 16; off <<= 1) {
                ps += __shfl_xor(ps, off);
                pd += __shfl_xor(pd, off);
            }
            if (il == 0) {
                ssT[bh * NN + jr + reg] = ps;
                sdT[bh * NN + jr + reg] = pd;
            }
        }
    }
}

// ---------------------------------------------------------------------------
// Kernel 2 (MFMA attn): out[b,i,h,:] = (sum_j q_ij g[j,:]) / (sum_j q_ij),
// q_ij = exp(lrelu(ss_i+sd_j) - m_i), m_i = lrelu(ss_i + max_j sd_j).
// WG = (b, h, 64-i-block), 4 waves (iw x jw): wave owns 32 i-rows (2 m-tiles
// sharing each gT B-frag -> half the gT traffic) x 512-j half. Barrier-free
// main loop; j-halves combined via LDS at the end. Grid 1024 -> 4 waves/SIMD.
// ---------------------------------------------------------------------------
__global__ __launch_bounds__(256) void gat_attn_kernel(
    const unsigned short* __restrict__ gT, const float* __restrict__ ssT,
    const float* __restrict__ sdT, float* __restrict__ out)
{
    __shared__ __align__(16) float sd_lds[NN];      // 4 KB
    __shared__ float red[4];
    __shared__ float s_part[2][64];
    __shared__ __align__(16) float c_lds[2][64][16];  // 8 KB

    const int b = blockIdx.z, h = blockIdx.y, i0 = blockIdx.x * 64;
    const int t = threadIdx.x, lane = t & 63, wv = t >> 6;
    const int iw = wv & 1, jw = wv >> 1;
    const int il = lane & 15, ql = lane >> 4;
    const int bh = b * NH + h;

    // stage sd + exact global max over j
    float M = -3.0e38f;
    #pragma unroll
    for (int q = 0; q < 4; ++q) {
        const float v = sdT[bh * NN + t + 256 * q];
        sd_lds[t + 256 * q] = v;
        M = fmaxf(M, v);
    }
    #pragma unroll
    for (int off = 32; off >= 1; off >>= 1)
        M = fmaxf(M, __shfl_xor(M, off));
    if (lane == 0) red[wv] = M;
    __syncthreads();
    M = fmaxf(fmaxf(red[0], red[1]), fmaxf(red[2], red[3]));

    const float si0 = ssT[bh * NN + i0 + iw * 32 + il];
    const float si1 = ssT[bh * NN + i0 + iw * 32 + 16 + il];
    float x0 = si0 + M; x0 = fmaxf(x0, 0.2f * x0);
    float x1 = si1 + M; x1 = fmaxf(x1, 0.2f * x1);
    const float mk0 = x0 * LOG2E, mk1 = x1 * LOG2E;

    const unsigned short* gb0 = gT + ((size_t)(bh * ND) + il) * NN + jw * 512 + ql * 8;
    const unsigned short* gb1 = gb0 + 16 * NN;
    const int sdbase = jw * 512 + ql * 8;

    f32x4 c00 = {0.f, 0.f, 0.f, 0.f}, c01 = c00, c10 = c00, c11 = c00;
    float S0 = 0.f, S1 = 0.f;

    #pragma unroll 2
    for (int kk = 0; kk < 512; kk += 32) {
        const float4 s0 = *(const float4*)&sd_lds[sdbase + kk];
        const float4 s1 = *(const float4*)&sd_lds[sdbase + kk + 4];
        const bf16x8 bf0 = *(const bf16x8*)(gb0 + kk);
        const bf16x8 bf1 = *(const bf16x8*)(gb1 + kk);

        float sv[8] = {s0.x, s0.y, s0.z, s0.w, s1.x, s1.y, s1.z, s1.w};
        float e0[8], e1[8];
        #pragma unroll
        for (int i = 0; i < 8; ++i) {
            float x = si0 + sv[i]; x = fmaxf(x, 0.2f * x);
            e0[i] = exp2f(fmaf(x, LOG2E, -mk0));
            x = si1 + sv[i]; x = fmaxf(x, 0.2f * x);
            e1[i] = exp2f(fmaf(x, LOG2E, -mk1));
        }
        #pragma unroll
        for (int i = 0; i < 8; ++i) { S0 += e0[i]; S1 += e1[i]; }

        union { bf16x8 v; unsigned u[4]; } af0, af1;
        #pragma unroll
        for (int i = 0; i < 4; ++i) {
            af0.u[i] = pk_bf16(e0[2 * i], e0[2 * i + 1]);
            af1.u[i] = pk_bf16(e1[2 * i], e1[2 * i + 1]);
        }

        c00 = __builtin_amdgcn_mfma_f32_16x16x32_bf16(af0.v, bf0, c00, 0, 0, 0);
        c01 = __builtin_amdgcn_mfma_f32_16x16x32_bf16(af0.v, bf1, c01, 0, 0, 0);
        c10 = __builtin_amdgcn_mfma_f32_16x16x32_bf16(af1.v, bf0, c10, 0, 0, 0);
        c11 = __builtin_amdgcn_mfma_f32_16x16x32_bf16(af1.v, bf1, c11, 0, 0, 0);
    }

    // complete S over the wave's j-half (sum 4 ql groups)
    S0 += __shfl_xor(S0, 16); S0 += __shfl_xor(S0, 32);
    S1 += __shfl_xor(S1, 16); S1 += __shfl_xor(S1, 32);
    if (lane < 16) {
        s_part[jw][iw * 32 + lane]      = S0;
        s_part[jw][iw * 32 + 16 + lane] = S1;
    }
    __syncthreads();

    if (jw == 1) {   // publish C frags for combine
        float* cp = &c_lds[iw][lane][0];
        *(f32x4*)(cp + 0)  = c00;
        *(f32x4*)(cp + 4)  = c01;
        *(f32x4*)(cp + 8)  = c10;
        *(f32x4*)(cp + 12) = c11;
    }
    __syncthreads();

    if (jw == 0) {
        const float* cp = &c_lds[iw][lane][0];
        c00 = c00 + *(const f32x4*)(cp + 0);
        c01 = c01 + *(const f32x4*)(cp + 4);
        c10 = c10 + *(const f32x4*)(cp + 8);
        c11 = c11 + *(const f32x4*)(cp + 12);

        const int rl = iw * 32 + ql * 4;
        float r0[4], r1[4];
        #pragma unroll
        for (int reg = 0; reg < 4; ++reg) {
            r0[reg] = 1.0f / (s_part[0][rl + reg]      + s_part[1][rl + reg]);
            r1[reg] = 1.0f / (s_part[0][rl + 16 + reg] + s_part[1][rl + 16 + reg]);
        }
        float* ob = out + (size_t)(b * NN + i0 + iw * 32 + ql * 4) * NOUT + h * ND + il;
        #pragma unroll
        for (int reg = 0; reg < 4; ++reg) {
            ob[reg * NOUT]                  = c00[reg] * r0[reg];
            ob[reg * NOUT + 16]             = c01[reg] * r0[reg];
            ob[(16 + reg) * NOUT]           = c10[reg] * r1[reg];
            ob[(16 + reg) * NOUT + 16]      = c11[reg] * r1[reg];
        }
    }
}

// ---------------------------------------------------------------------------
extern "C" void kernel_launch(void* const* d_in, const int* in_sizes, int n_in,
                              void* d_out, int out_size, void* d_ws, size_t ws_size,
                              hipStream_t stream) {
    (void)in_sizes; (void)n_in; (void)out_size; (void)ws_size;
    const float* vertex = (const float*)d_in[0];
    const float* w_vert = (const float*)d_in[1];
    const float* attn_w = (const float*)d_in[2];
    float* out = (float*)d_out;

    char* ws = (char*)d_ws;
    unsigned short* wT_hi = (unsigned short*)ws;                       // 128 KB
    unsigned short* wT_lo = (unsigned short*)(ws + (128 << 10));       // 128 KB
    unsigned short* gT    = (unsigned short*)(ws + (256 << 10));       // 4 MB
    float* ssT = (float*)(ws + (256 << 10) + ((size_t)NB * NH * ND * NN * 2));
    float* sdT = ssT + (size_t)NB * NH * NN;

    w_prep_kernel<<<16, 256, 0, stream>>>(w_vert, wT_hi, wT_lo);
    gat_gemm_kernel<<<dim3(4, 128), 256, 0, stream>>>(vertex, wT_hi, wT_lo,
                                                      attn_w, gT, ssT, sdT);
    gat_attn_kernel<<<dim3(16, NH, NB), 256, 0, stream>>>(gT, ssT, sdT, out);
}

// Round 5
// 100.590 us; speedup vs baseline: 1.9081x; 1.0795x over previous
//
#include <hip/hip_runtime.h>
#include <hip/hip_bf16.h>
#include <math.h>

// Problem constants
#define F_IN  256
#define NOUT  256          // N_HEADS * N_HIDDEN
#define NB    8            // batch
#define NN    1024         // nodes
#define NH    8            // heads
#define ND    32           // hidden per head
#define NROWS (NB * NN)    // 8192
#define LOG2E 1.44269504f

typedef __attribute__((ext_vector_type(8))) short bf16x8;   // 8 bf16 = 4 VGPRs
typedef __attribute__((ext_vector_type(4))) float f32x4;    // MFMA C/D

__device__ inline unsigned pk_bf16(float a, float b) {
    union { __hip_bfloat162 h2; unsigned u; } c;
    c.h2 = __float22bfloat162_rn(make_float2(a, b));
    return c.u;
}
__device__ inline unsigned short bf16u(float a) {
    union { __hip_bfloat16 h; unsigned short u; } c;
    c.h = __float2bfloat16(a);
    return c.u;
}
__device__ inline float bf2f(unsigned short u) {
    union { unsigned u; float f; } c;
    c.u = ((unsigned)u) << 16;
    return c.f;
}
// split 8 fp32 into hi/lo bf16 fragments (hi = rn(x), lo = rn(x - hi))
__device__ inline void split8(const float4 va, const float4 vb,
                              bf16x8& hi, bf16x8& lo) {
    float f[8] = {va.x, va.y, va.z, va.w, vb.x, vb.y, vb.z, vb.w};
    union { bf16x8 v; unsigned u[4]; } H, L;
    #pragma unroll
    for (int i = 0; i < 4; ++i) {
        unsigned short h0 = bf16u(f[2 * i]);
        unsigned short h1 = bf16u(f[2 * i + 1]);
        H.u[i] = (unsigned)h0 | ((unsigned)h1 << 16);
        L.u[i] = pk_bf16(f[2 * i] - bf2f(h0), f[2 * i + 1] - bf2f(h1));
    }
    hi = H.v; lo = L.v;
}

// ---------------------------------------------------------------------------
// Kernel 0: wT_hi/wT_lo [n][k] bf16 split of w_vert [k][n] fp32 (one-time).
// ---------------------------------------------------------------------------
__global__ __launch_bounds__(256) void w_prep_kernel(
    const float* __restrict__ w_vert,
    unsigned short* __restrict__ wT_hi, unsigned short* __restrict__ wT_lo)
{
    __shared__ float wf[64][68];
    const int t  = threadIdx.x;
    const int kt = (blockIdx.x >> 2) * 64;
    const int nt = (blockIdx.x & 3) * 64;
    #pragma unroll
    for (int q = 0; q < 4; ++q) {
        const int kr = (t >> 4) + 16 * q;
        const int nc = (t & 15) * 4;
        float4 v = *(const float4*)&w_vert[(size_t)(kt + kr) * NOUT + nt + nc];
        wf[kr][nc + 0] = v.x; wf[kr][nc + 1] = v.y;
        wf[kr][nc + 2] = v.z; wf[kr][nc + 3] = v.w;
    }
    __syncthreads();
    const int n = t >> 2, ks = (t & 3) * 16;
    union { unsigned u[8]; } Hs, Ls;
    #pragma unroll
    for (int i = 0; i < 8; ++i) {
        float x0 = wf[ks + 2 * i][n], x1 = wf[ks + 2 * i + 1][n];
        unsigned short h0 = bf16u(x0), h1 = bf16u(x1);
        Hs.u[i] = (unsigned)h0 | ((unsigned)h1 << 16);
        Ls.u[i] = pk_bf16(x0 - bf2f(h0), x1 - bf2f(h1));
    }
    unsigned* ph = (unsigned*)(wT_hi + (size_t)(nt + n) * F_IN + kt + ks);
    unsigned* pl = (unsigned*)(wT_lo + (size_t)(nt + n) * F_IN + kt + ks);
    #pragma unroll
    for (int i = 0; i < 8; ++i) { ph[i] = Hs.u[i]; pl[i] = Ls.u[i]; }
}

// ---------------------------------------------------------------------------
// Kernel 1: g = vertex @ w_vert via split-bf16 MFMA, split-k 2-way for
// occupancy (4 waves/SIMD vs R4's 2). WG = 64 rows x 32 cols (1 head),
// 4 waves = (m-tile 0/1) x (k-half 0/1); wave = 32x32x128, 12 MFMAs/k-step.
// k-halves combined via LDS; epilogue: gT bf16 [bh][d][j] + fp32 scores.
// Grid (8 heads, 128 row-blocks) = 1024 WGs -> 4 WG/CU.
// ---------------------------------------------------------------------------
__global__ __launch_bounds__(256) void gat_gemm_kernel(
    const float* __restrict__ vertex,
    const unsigned short* __restrict__ wT_hi,
    const unsigned short* __restrict__ wT_lo,
    const float* __restrict__ attn_w, unsigned short* __restrict__ gT,
    float* __restrict__ ssT, float* __restrict__ sdT)
{
    __shared__ f32x4 comb[2][4][64];   // 8 KB: k-half-1 C-frag publish

    const int t = threadIdx.x, lane = t & 63, wv = t >> 6;
    const int mt = wv & 1, kh = wv >> 1;
    const int il = lane & 15, ql = lane >> 4;
    const int h = blockIdx.x, gr0 = blockIdx.y * 64;
    const int b = gr0 >> 10, bh = b * NH + h;

    const float* arow0 = vertex + (size_t)(gr0 + mt * 32 + il) * F_IN + kh * 128 + ql * 8;
    const float* arow1 = arow0 + 16 * F_IN;
    const unsigned short* b0h = wT_hi + (size_t)(h * 32 + il) * F_IN + kh * 128 + ql * 8;
    const unsigned short* b1h = b0h + 16 * F_IN;
    const unsigned short* b0l = wT_lo + (size_t)(h * 32 + il) * F_IN + kh * 128 + ql * 8;
    const unsigned short* b1l = b0l + 16 * F_IN;

    f32x4 c00 = {0.f, 0.f, 0.f, 0.f}, c01 = c00, c10 = c00, c11 = c00;

    #pragma unroll 2
    for (int kk = 0; kk < 128; kk += 32) {
        float4 a0a = *(const float4*)(arow0 + kk);
        float4 a0b = *(const float4*)(arow0 + kk + 4);
        float4 a1a = *(const float4*)(arow1 + kk);
        float4 a1b = *(const float4*)(arow1 + kk + 4);
        bf16x8 bh0 = *(const bf16x8*)(b0h + kk);
        bf16x8 bh1 = *(const bf16x8*)(b1h + kk);
        bf16x8 bl0 = *(const bf16x8*)(b0l + kk);
        bf16x8 bl1 = *(const bf16x8*)(b1l + kk);

        bf16x8 a0hi, a0lo, a1hi, a1lo;
        split8(a0a, a0b, a0hi, a0lo);
        split8(a1a, a1b, a1hi, a1lo);

        c00 = __builtin_amdgcn_mfma_f32_16x16x32_bf16(a0hi, bh0, c00, 0, 0, 0);
        c01 = __builtin_amdgcn_mfma_f32_16x16x32_bf16(a0hi, bh1, c01, 0, 0, 0);
        c10 = __builtin_amdgcn_mfma_f32_16x16x32_bf16(a1hi, bh0, c10, 0, 0, 0);
        c11 = __builtin_amdgcn_mfma_f32_16x16x32_bf16(a1hi, bh1, c11, 0, 0, 0);
        c00 = __builtin_amdgcn_mfma_f32_16x16x32_bf16(a0lo, bh0, c00, 0, 0, 0);
        c01 = __builtin_amdgcn_mfma_f32_16x16x32_bf16(a0lo, bh1, c01, 0, 0, 0);
        c10 = __builtin_amdgcn_mfma_f32_16x16x32_bf16(a1lo, bh0, c10, 0, 0, 0);
        c11 = __builtin_amdgcn_mfma_f32_16x16x32_bf16(a1lo, bh1, c11, 0, 0, 0);
        c00 = __builtin_amdgcn_mfma_f32_16x16x32_bf16(a0hi, bl0, c00, 0, 0, 0);
        c01 = __builtin_amdgcn_mfma_f32_16x16x32_bf16(a0hi, bl1, c01, 0, 0, 0);
        c10 = __builtin_amdgcn_mfma_f32_16x16x32_bf16(a1hi, bl0, c10, 0, 0, 0);
        c11 = __builtin_amdgcn_mfma_f32_16x16x32_bf16(a1hi, bl1, c11, 0, 0, 0);
    }

    if (kh == 1) {
        comb[mt][0][lane] = c00; comb[mt][1][lane] = c01;
        comb[mt][2][lane] = c10; comb[mt][3][lane] = c11;
    }
    __syncthreads();
    if (kh == 0) {
        c00 = c00 + comb[mt][0][lane]; c01 = c01 + comb[mt][1][lane];
        c10 = c10 + comb[mt][2][lane]; c11 = c11 + comb[mt][3][lane];

        // epilogue: rows gr0+mt*32..+31, cols h*32..+31.
        // C/D: col=il, row=ql*4+reg.
        const int j0 = (gr0 & 1023) + mt * 32;
        const float wsv0 = attn_w[il],      wsv1 = attn_w[16 + il];
        const float wdv0 = attn_w[ND + il], wdv1 = attn_w[ND + 16 + il];

        #pragma unroll
        for (int g = 0; g < 2; ++g) {
            f32x4 cA = g ? c10 : c00;   // d = il
            f32x4 cB = g ? c11 : c01;   // d = 16+il
            const int jr = j0 + g * 16 + ql * 4;

            unsigned g2[2];
            g2[0] = pk_bf16(cA[0], cA[1]); g2[1] = pk_bf16(cA[2], cA[3]);
            *(uint2*)(gT + ((size_t)(bh * ND) + il) * NN + jr) = *(uint2*)g2;
            g2[0] = pk_bf16(cB[0], cB[1]); g2[1] = pk_bf16(cB[2], cB[3]);
            *(uint2*)(gT + ((size_t)(bh * ND) + 16 + il) * NN + jr) = *(uint2*)g2;

            #pragma unroll
            for (int reg = 0; reg < 4; ++reg) {
                float ps = cA[reg] * wsv0 + cB[reg] * wsv1;
                float pd = cA[reg] * wdv0 + cB[reg] * wdv1;
                #pragma unroll
                for (int off = 1; off < 16; off <<= 1) {
                    ps += __shfl_xor(ps, off);
                    pd += __shfl_xor(pd, off);
                }
                if (il == 0) {
                    ssT[bh * NN + jr + reg] = ps;
                    sdT[bh * NN + jr + reg] = pd;
                }
            }
        }
    }
}

// ---------------------------------------------------------------------------
// Kernel 2 (exp-free MFMA attn):
//   q_ij = exp(lrelu(ss_i+sd_j) - m_i) factorizes per lrelu branch:
//   q_ij = cond ? Ap_i*Bp_j : An_i*Bn_j,  cond = (sd_j >= -ss_i) = (Bp_j >= T_i)
//   with Bp_j = 2^(sd_j*c), Bn_j = 2^(0.2*sd_j*c)  (c = log2 e, LDS arrays),
//   Ap_i = 2^(ss_i*c - mk_i), An_i = 2^(0.2*ss_i*c - mk_i), T_i = 2^(-ss_i*c).
//   => inner loop has ZERO transcendentals: cmp + 2*cndmask + mul per q.
// Denominator S_i via a 3rd MFMA against an all-ones B-frag (C-layout direct).
// WG = (b, h, 32-i-block), 4 waves = j-quarters (256 j each); barrier-free
// main loop; quarter combine via LDS tree. Grid 2048 WGs.
// ---------------------------------------------------------------------------
__global__ __launch_bounds__(256) void gat_attn_kernel(
    const unsigned short* __restrict__ gT, const float* __restrict__ ssT,
    const float* __restrict__ sdT, float* __restrict__ out)
{
    __shared__ __align__(16) float Bp[NN];     // 4 KB
    __shared__ __align__(16) float Bn[NN];     // 4 KB
    __shared__ float red[4];
    __shared__ f32x4 comb[2][6][64];           // 12 KB combine buffer

    const int b = blockIdx.z, h = blockIdx.y, i0 = blockIdx.x * 32;
    const int t = threadIdx.x, lane = t & 63, jq = t >> 6;
    const int il = lane & 15, ql = lane >> 4;
    const int bh = b * NH + h;

    // ---- phase 0: global max of sd; Bp/Bn arrays; per-lane i-constants ----
    float sdv[4]; float M = -3.0e38f;
    #pragma unroll
    for (int q = 0; q < 4; ++q) {
        sdv[q] = sdT[bh * NN + t + 256 * q];
        M = fmaxf(M, sdv[q]);
    }
    #pragma unroll
    for (int off = 32; off >= 1; off >>= 1)
        M = fmaxf(M, __shfl_xor(M, off));
    if (lane == 0) red[jq] = M;
    __syncthreads();
    M = fmaxf(fmaxf(red[0], red[1]), fmaxf(red[2], red[3]));

    #pragma unroll
    for (int q = 0; q < 4; ++q) {
        Bp[t + 256 * q] = exp2f(sdv[q] * LOG2E);
        Bn[t + 256 * q] = exp2f(0.2f * LOG2E * sdv[q]);
    }
    const float si0 = ssT[bh * NN + i0 + il];
    const float si1 = ssT[bh * NN + i0 + 16 + il];
    float x0 = si0 + M; x0 = fmaxf(x0, 0.2f * x0);
    float x1 = si1 + M; x1 = fmaxf(x1, 0.2f * x1);
    const float mk0 = x0 * LOG2E, mk1 = x1 * LOG2E;
    const float Ap0 = exp2f(fmaf(si0, LOG2E, -mk0));
    const float An0 = exp2f(fmaf(0.2f * si0, LOG2E, -mk0));
    const float T0  = exp2f(-si0 * LOG2E);
    const float Ap1 = exp2f(fmaf(si1, LOG2E, -mk1));
    const float An1 = exp2f(fmaf(0.2f * si1, LOG2E, -mk1));
    const float T1  = exp2f(-si1 * LOG2E);
    __syncthreads();

    // ---- main loop: wave jq handles j in [jq*256, jq*256+256) ----
    const unsigned short* gb0 = gT + ((size_t)(bh * ND) + il) * NN + jq * 256 + ql * 8;
    const unsigned short* gb1 = gb0 + 16 * NN;
    const float* bpq = &Bp[jq * 256 + ql * 8];
    const float* bnq = &Bn[jq * 256 + ql * 8];

    union { bf16x8 v; unsigned u[4]; } ones;
    ones.u[0] = ones.u[1] = ones.u[2] = ones.u[3] = 0x3F803F80u;

    f32x4 c00 = {0.f, 0.f, 0.f, 0.f}, c01 = c00, c10 = c00, c11 = c00;
    f32x4 cs0 = c00, cs1 = c00;

    #pragma unroll 2
    for (int kk = 0; kk < 256; kk += 32) {
        const float4 p0 = *(const float4*)(bpq + kk);
        const float4 p1 = *(const float4*)(bpq + kk + 4);
        const float4 n0 = *(const float4*)(bnq + kk);
        const float4 n1 = *(const float4*)(bnq + kk + 4);
        const bf16x8 bf0 = *(const bf16x8*)(gb0 + kk);
        const bf16x8 bf1 = *(const bf16x8*)(gb1 + kk);

        float pv[8] = {p0.x, p0.y, p0.z, p0.w, p1.x, p1.y, p1.z, p1.w};
        float nv[8] = {n0.x, n0.y, n0.z, n0.w, n1.x, n1.y, n1.z, n1.w};
        float e0[8], e1[8];
        #pragma unroll
        for (int u = 0; u < 8; ++u) {
            const bool cA = pv[u] >= T0;
            e0[u] = (cA ? Ap0 : An0) * (cA ? pv[u] : nv[u]);
            const bool cB = pv[u] >= T1;
            e1[u] = (cB ? Ap1 : An1) * (cB ? pv[u] : nv[u]);
        }

        union { bf16x8 v; unsigned u[4]; } af0, af1;
        #pragma unroll
        for (int u = 0; u < 4; ++u) {
            af0.u[u] = pk_bf16(e0[2 * u], e0[2 * u + 1]);
            af1.u[u] = pk_bf16(e1[2 * u], e1[2 * u + 1]);
        }

        c00 = __builtin_amdgcn_mfma_f32_16x16x32_bf16(af0.v, bf0, c00, 0, 0, 0);
        c01 = __builtin_amdgcn_mfma_f32_16x16x32_bf16(af0.v, bf1, c01, 0, 0, 0);
        cs0 = __builtin_amdgcn_mfma_f32_16x16x32_bf16(af0.v, ones.v, cs0, 0, 0, 0);
        c10 = __builtin_amdgcn_mfma_f32_16x16x32_bf16(af1.v, bf0, c10, 0, 0, 0);
        c11 = __builtin_amdgcn_mfma_f32_16x16x32_bf16(af1.v, bf1, c11, 0, 0, 0);
        cs1 = __builtin_amdgcn_mfma_f32_16x16x32_bf16(af1.v, ones.v, cs1, 0, 0, 0);
    }

    // ---- quarter combine (tree): 2,3 -> 0,1; then 1 -> 0 ----
    if (jq >= 2) {
        comb[jq - 2][0][lane] = c00; comb[jq - 2][1][lane] = c01;
        comb[jq - 2][2][lane] = c10; comb[jq - 2][3][lane] = c11;
        comb[jq - 2][4][lane] = cs0; comb[jq - 2][5][lane] = cs1;
    }
    __syncthreads();
    if (jq < 2) {
        c00 = c00 + comb[jq][0][lane]; c01 = c01 + comb[jq][1][lane];
        c10 = c10 + comb[jq][2][lane]; c11 = c11 + comb[jq][3][lane];
        cs0 = cs0 + comb[jq][4][lane]; cs1 = cs1 + comb[jq][5][lane];
    }
    __syncthreads();
    if (jq == 1) {
        comb[0][0][lane] = c00; comb[0][1][lane] = c01;
        comb[0][2][lane] = c10; comb[0][3][lane] = c11;
        comb[0][4][lane] = cs0; comb[0][5][lane] = cs1;
    }
    __syncthreads();
    if (jq == 0) {
        c00 = c00 + comb[0][0][lane]; c01 = c01 + comb[0][1][lane];
        c10 = c10 + comb[0][2][lane]; c11 = c11 + comb[0][3][lane];
        cs0 = cs0 + comb[0][4][lane]; cs1 = cs1 + comb[0][5][lane];

        // C/D: col=il (d), row=ql*4+reg (i). cs*[reg] = S_i (all cols equal).
        float r0[4], r1[4];
        #pragma unroll
        for (int reg = 0; reg < 4; ++reg) {
            r0[reg] = 1.0f / cs0[reg];
            r1[reg] = 1.0f / cs1[reg];
        }
        float* ob = out + (size_t)(b * NN + i0 + ql * 4) * NOUT + h * ND + il;
        #pragma unroll
        for (int reg = 0; reg < 4; ++reg) {
            ob[reg * NOUT]             = c00[reg] * r0[reg];
            ob[reg * NOUT + 16]        = c01[reg] * r0[reg];
            ob[(16 + reg) * NOUT]      = c10[reg] * r1[reg];
            ob[(16 + reg) * NOUT + 16] = c11[reg] * r1[reg];
        }
    }
}

// ---------------------------------------------------------------------------
extern "C" void kernel_launch(void* const* d_in, const int* in_sizes, int n_in,
                              void* d_out, int out_size, void* d_ws, size_t ws_size,
                              hipStream_t stream) {
    (void)in_sizes; (void)n_in; (void)out_size; (void)ws_size;
    const float* vertex = (const float*)d_in[0];
    const float* w_vert = (const float*)d_in[1];
    const float* attn_w = (const float*)d_in[2];
    float* out = (float*)d_out;

    char* ws = (char*)d_ws;
    unsigned short* wT_hi = (unsigned short*)ws;                       // 128 KB
    unsigned short* wT_lo = (unsigned short*)(ws + (128 << 10));       // 128 KB
    unsigned short* gT    = (unsigned short*)(ws + (256 << 10));       // 4 MB
    float* ssT = (float*)(ws + (256 << 10) + ((size_t)NB * NH * ND * NN * 2));
    float* sdT = ssT + (size_t)NB * NH * NN;

    w_prep_kernel<<<16, 256, 0, stream>>>(w_vert, wT_hi, wT_lo);
    gat_gemm_kernel<<<dim3(NH, 128), 256, 0, stream>>>(vertex, wT_hi, wT_lo,
                                                       attn_w, gT, ssT, sdT);
    gat_attn_kernel<<<dim3(32, NH, NB), 256, 0, stream>>>(gT, ssT, sdT, out);
}